// Round 2
// baseline (173.302 us; speedup 1.0000x reference)
//
#include <hip/hip_runtime.h>

// GNN surrogate — r19: half8-native register state, spill kill + occupancy.
// r18 counters: WRITE_SIZE 128->2690 KB (scratch spills), occ ~20% (2 w/SIMD,
// 128 VGPR + hidden AGPR accs ~= 192 granule), MfmaUtil 25 / VALUBusy 25 /
// HBM 2.8 -> latency-bound. Root cause: cat() built explicit half4->half8
// copy pairs; tf(32) + cats(32) + pf(32) live simultaneously.
// Fix: state IS the operand. L0/L1 emit cat(relupk(c_g), relupk(c_{g+1}))
// directly (G-friendly node-pair axis); GSTEP emits cat(pkc(a0), pkc(a1))
// directly (L-friendly fout-pair axis). Persistent state = 8 half8 ca/cb
// ping-ponged with 8 half8 pf = 64 VGPR. Bit-identical values to r18.
// __launch_bounds__(256,3): 168-reg unified budget -> 3 waves/SIMD, chosen
// over (256,4)'s 128 budget to stay clear of the r15/r16 spill cliff.

typedef _Float16 f16;
typedef __attribute__((ext_vector_type(8))) _Float16 half8;
typedef __attribute__((ext_vector_type(4))) _Float16 half4;
typedef __attribute__((ext_vector_type(2))) __fp16 fp16x2;
typedef __attribute__((ext_vector_type(4))) float f32x4;

namespace {
constexpr int N = 128, H = 32;
constexpr int WS_ADJB = 0;       // f16 [8gi][4c][64lane][8] K=32 adj B-tiles (32768 B)
constexpr int WS_W0B  = 32768;   // f16 [2t][64lane][4]  W1eff K=16 B-tiles   (1024 B)
constexpr int WS_MB   = 33792;   // f16 [2l][2t][64lane][8] Meff K=32 B-tiles (4096 B)
constexpr int WS_BIAS = 37888;   // f32 [3][32]
constexpr int WS_V    = 38400;   // f32 [128]
constexpr int WS_U    = 38912;   // f32 [32]
constexpr int WS_C    = 39040;   // f32 [1]
}

static __device__ __forceinline__ half4 pk4(float a, float b, float c, float d) {
  union { half4 v; fp16x2 h[2]; } u;
  u.h[0] = __builtin_amdgcn_cvt_pkrtz(a, b);
  u.h[1] = __builtin_amdgcn_cvt_pkrtz(c, d);
  return u.v;
}
static __device__ __forceinline__ half4 relupk(f32x4 c) {
  const half4 z = {};
  return __builtin_elementwise_max(pk4(c[0], c[1], c[2], c[3]), z);
}
static __device__ __forceinline__ half4 pkc(f32x4 c) {
  return pk4(c[0], c[1], c[2], c[3]);
}
static __device__ __forceinline__ half8 cat(half4 lo, half4 hi) {
  return __builtin_shufflevector(lo, hi, 0, 1, 2, 3, 4, 5, 6, 7);
}

#define MF(A, B, C)   __builtin_amdgcn_mfma_f32_16x16x16f16((A), (B), (C), 0, 0, 0)
#define MF32(A, B, C) __builtin_amdgcn_mfma_f32_16x16x32_f16((A), (B), (C), 0, 0, 0)

// ---- prep: identical to r18 (verified) ----
__global__ void prep(const float* __restrict__ adj,
                     const float* __restrict__ W_lift,
                     const float* __restrict__ b_lift,
                     const float* __restrict__ W1,
                     const float* __restrict__ b1,
                     const float* __restrict__ W2,
                     const float* __restrict__ b2,
                     const float* __restrict__ W_ro,
                     const float* __restrict__ b_ro,
                     char* __restrict__ ws) {
  const int tid = threadIdx.x;
  f16* adjb  = (f16*)(ws + WS_ADJB);
  f16* w0b   = (f16*)(ws + WS_W0B);
  f16* mb    = (f16*)(ws + WS_MB);
  float* bia = (float*)(ws + WS_BIAS);
  float* v   = (float*)(ws + WS_V);
  float* u   = (float*)(ws + WS_U);
  float* cp  = (float*)(ws + WS_C);

  if (blockIdx.x != 0) {
    for (int e = tid; e < 2048; e += 256) {
      const int gi = e >> 8, c = (e >> 6) & 3, lane = e & 63;
      const int lr = lane & 15, q = lane >> 4;
      const float* src = adj + (gi * 16 + lr) * N + c * 32;
      f16* dst = adjb + e * 8;
#pragma unroll
      for (int j = 0; j < 8; ++j) {
        const int col = (j < 4) ? (4 * q + j) : (12 + 4 * q + j);  // lambda
        dst[j] = (f16)src[col];
      }
    }
    return;
  }

  __shared__ float tmp[3][H][H];
  __shared__ float sred[N];
  for (int idx = tid; idx < 3 * H * H; idx += 256) {
    const int l = idx >> 10, rem = idx & 1023;
    const int k = rem >> 5, fo = rem & 31;
    float val = 0.f;
    if (l == 0) {
      if (k < 3) for (int c = 0; c < H; ++c) val += W_lift[k * H + c] * W1[c * H + fo];
    } else {
      const float* w2l = W2 + (l - 1) * H * H;
      const float* w1n = W1 + l * H * H;
      for (int c = 0; c < H; ++c) val += w2l[k * H + c] * w1n[c * H + fo];
    }
    tmp[l][k][fo] = val;
  }
  if (tid < N) {
    float s = 0.f;
    for (int i = 0; i < N; ++i) s += adj[i * N + tid];
    v[tid] = s * (1.0f / N);
    sred[tid] = s * (1.0f / N);
  }
  if (tid < H) {
    float s0 = b1[tid], s1 = b1[H + tid], s2 = b1[2 * H + tid];
    for (int c = 0; c < H; ++c) {
      s0 += b_lift[c] * W1[c * H + tid];
      s1 += b2[c] * W1[H * H + c * H + tid];
      s2 += b2[H + c] * W1[2 * H * H + c * H + tid];
    }
    bia[tid] = s0; bia[H + tid] = s1; bia[2 * H + tid] = s2;
    float su = 0.f;
    for (int c = 0; c < H; ++c) su += W2[2 * H * H + tid * H + c] * W_ro[c];
    u[tid] = su;
  }
  __syncthreads();
  for (int e = tid; e < 512; e += 256) {
    const int t = e >> 8, lane = (e >> 2) & 63, j = e & 3;
    const int lr = lane & 15, q = lane >> 4;
    w0b[e] = (f16)tmp[0][q * 4 + j][t * 16 + lr];
  }
  for (int e = tid; e < 2048; e += 256) {
    const int l = e >> 10, rem = e & 1023;
    const int t = rem >> 9, lane = (rem >> 3) & 63, j = rem & 7;
    const int lr = lane & 15, q = lane >> 4;
    const int k = (j < 4) ? (4 * q + j) : (12 + 4 * q + j);  // lambda
    mb[e] = (f16)tmp[1 + l][k][t * 16 + lr];
  }
  if (tid < 64) {
    float s = sred[tid] + sred[64 + tid];
#pragma unroll
    for (int off = 32; off > 0; off >>= 1) s += __shfl_down(s, off, 64);
    if (tid == 0) {
      float c2r = 0.f;
      for (int k = 0; k < H; ++k) c2r += b2[2 * H + k] * W_ro[k];
      cp[0] = c2r * s + b_ro[0];
    }
  }
}

__global__ __launch_bounds__(256, 3)
void gnn_mfma(const float* __restrict__ x,
              const char* __restrict__ ws,
              float* __restrict__ out) {
  const f16* adjb  = (const f16*)(ws + WS_ADJB);
  const f16* w0b   = (const f16*)(ws + WS_W0B);
  const f16* mb    = (const f16*)(ws + WS_MB);
  const float* bia = (const float*)(ws + WS_BIAS);
  const float* v   = (const float*)(ws + WS_V);
  const float* u   = (const float*)(ws + WS_U);
  const float* cp  = (const float*)(ws + WS_C);

  const int tid  = threadIdx.x;
  const int wave = tid >> 6;
  const int lane = tid & 63;
  const int lrow = lane & 15;
  const int quad = lane >> 4;
  const int b    = blockIdx.x * 4 + wave;

  const f32x4 zero = {0.f, 0.f, 0.f, 0.f};

  // Persistent state: 8 half8 (32 VGPR) ping-ponged with 8 half8 (32 VGPR).
  // ca_p/cb_p = [fout block][node-pair 2p,2p+1]  (G-stage A operands)
  // pf_g      = [fout blocks 0|1 concat][group g] (L-stage A operands)
  half8 ca0, ca1, ca2, ca3, cb0, cb1, cb2, cb3;
  half8 pf0, pf1, pf2, pf3, pf4, pf5, pf6, pf7;

  // ---- L0: T0 = relu(x·W1eff + b0), K=16 MFMA, emits G-friendly cats ----
  {
    const half4 w0 = *(const half4*)(w0b + (0 * 64 + lane) * 4);
    const half4 w1 = *(const half4*)(w0b + (1 * 64 + lane) * 4);
    const float bb0 = bia[lrow], bb1 = bia[16 + lrow];
    const f32x4 bi0 = {bb0, bb0, bb0, bb0};
    const f32x4 bi1 = {bb1, bb1, bb1, bb1};
#define L0PAIR(g, CA, CB)                                                    \
    {                                                                        \
      half4 xa0 = {}, xa1 = {};                                              \
      if (quad == 0) {                                                       \
        const float* xr0 = x + ((size_t)b * N + (g) * 16 + lrow) * 3;        \
        const float* xr1 = x + ((size_t)b * N + ((g) + 1) * 16 + lrow) * 3;  \
        xa0 = pk4(xr0[0], xr0[1], xr0[2], 0.f);                              \
        xa1 = pk4(xr1[0], xr1[1], xr1[2], 0.f);                              \
      }                                                                      \
      CA = cat(relupk(MF(xa0, w0, bi0)), relupk(MF(xa1, w0, bi0)));          \
      CB = cat(relupk(MF(xa0, w1, bi1)), relupk(MF(xa1, w1, bi1)));          \
    }
    L0PAIR(0, ca0, cb0) L0PAIR(2, ca1, cb1) L0PAIR(4, ca2, cb2) L0PAIR(6, ca3, cb3)
#undef L0PAIR
  }

  // G: pf_g = cat over fout blocks of P^T[t][nodes gi]; K=32 MFMAs.
#define GSTEP(gi, PF)                                                        \
  {                                                                          \
    f32x4 a0 = zero, a1 = zero;                                              \
    const f16* ab = adjb + ((gi) * 256 + lane) * 8;                          \
    half8 bt;                                                                \
    bt = *(const half8*)(ab + 0 * 512);                                      \
    a0 = MF32(ca0, bt, a0); a1 = MF32(cb0, bt, a1);                          \
    bt = *(const half8*)(ab + 1 * 512);                                      \
    a0 = MF32(ca1, bt, a0); a1 = MF32(cb1, bt, a1);                          \
    bt = *(const half8*)(ab + 2 * 512);                                      \
    a0 = MF32(ca2, bt, a0); a1 = MF32(cb2, bt, a1);                          \
    bt = *(const half8*)(ab + 3 * 512);                                      \
    a0 = MF32(ca3, bt, a0); a1 = MF32(cb3, bt, a1);                          \
    PF = cat(pkc(a0), pkc(a1));                                              \
  }
#define GALL()                                                               \
  GSTEP(0, pf0) GSTEP(1, pf1) GSTEP(2, pf2) GSTEP(3, pf3)                    \
  GSTEP(4, pf4) GSTEP(5, pf5) GSTEP(6, pf6) GSTEP(7, pf7)

  GALL()   // G0

  // L1: consumes pf pairs, emits G-friendly cats directly.
  {
    const f16* mbl = mb + 0 * 1024;
    const half8 m0 = *(const half8*)(mbl + (0 * 64 + lane) * 8);
    const half8 m1 = *(const half8*)(mbl + (1 * 64 + lane) * 8);
    const float bb0 = bia[H + lrow], bb1 = bia[H + 16 + lrow];
    const f32x4 bi0 = {bb0, bb0, bb0, bb0};
    const f32x4 bi1 = {bb1, bb1, bb1, bb1};
#define L1PAIR(PFA, PFB, CA, CB)                                             \
    {                                                                        \
      f32x4 c0a = MF32(PFA, m0, bi0);                                        \
      f32x4 c1a = MF32(PFA, m1, bi1);                                        \
      f32x4 c0b = MF32(PFB, m0, bi0);                                        \
      f32x4 c1b = MF32(PFB, m1, bi1);                                        \
      CA = cat(relupk(c0a), relupk(c0b));                                    \
      CB = cat(relupk(c1a), relupk(c1b));                                    \
    }
    L1PAIR(pf0, pf1, ca0, cb0) L1PAIR(pf2, pf3, ca1, cb1)
    L1PAIR(pf4, pf5, ca2, cb2) L1PAIR(pf6, pf7, ca3, cb3)
#undef L1PAIR
  }

  GALL()   // G1
#undef GALL
#undef GSTEP

  // ---- L2 + folded readout: consumes pf_g directly ----
  {
    const f16* mbl = mb + 1 * 1024;
    const half8 m0 = *(const half8*)(mbl + (0 * 64 + lane) * 8);
    const half8 m1 = *(const half8*)(mbl + (1 * 64 + lane) * 8);
    const float bb0 = bia[2 * H + lrow], bb1 = bia[2 * H + 16 + lrow];
    const f32x4 bi0 = {bb0, bb0, bb0, bb0};
    const f32x4 bi1 = {bb1, bb1, bb1, bb1};
    const float u0 = u[lrow], u1 = u[16 + lrow];
    float partial = 0.f;
#define L2G(g, PF)                                                           \
    {                                                                        \
      f32x4 c0 = MF32(PF, m0, bi0);                                          \
      f32x4 c1 = MF32(PF, m1, bi1);                                          \
      const float4 vv = *(const float4*)(v + (g) * 16 + quad * 4);           \
      partial += (fmaxf(c0[0], 0.f) * vv.x + fmaxf(c0[1], 0.f) * vv.y +      \
                  fmaxf(c0[2], 0.f) * vv.z + fmaxf(c0[3], 0.f) * vv.w) * u0 +\
                 (fmaxf(c1[0], 0.f) * vv.x + fmaxf(c1[1], 0.f) * vv.y +      \
                  fmaxf(c1[2], 0.f) * vv.z + fmaxf(c1[3], 0.f) * vv.w) * u1; \
    }
    L2G(0, pf0) L2G(1, pf1) L2G(2, pf2) L2G(3, pf3)
    L2G(4, pf4) L2G(5, pf5) L2G(6, pf6) L2G(7, pf7)
#undef L2G
#pragma unroll
    for (int off = 32; off > 0; off >>= 1) partial += __shfl_down(partial, off, 64);
    if (lane == 0) out[b] = partial + cp[0];
  }
}

extern "C" void kernel_launch(void* const* d_in, const int* in_sizes, int n_in,
                              void* d_out, int out_size, void* d_ws, size_t ws_size,
                              hipStream_t stream) {
  const float* x      = (const float*)d_in[0];
  const float* adj    = (const float*)d_in[1];
  const float* W_lift = (const float*)d_in[2];
  const float* b_lift = (const float*)d_in[3];
  const float* W1     = (const float*)d_in[4];
  const float* b1     = (const float*)d_in[5];
  const float* W2     = (const float*)d_in[6];
  const float* b2     = (const float*)d_in[7];
  const float* W_ro   = (const float*)d_in[8];
  const float* b_ro   = (const float*)d_in[9];
  char* ws = (char*)d_ws;
  float* o = (float*)d_out;

  const int B = in_sizes[0] / (N * 3);   // 16384
  hipLaunchKernelGGL(prep, dim3(2), dim3(256), 0, stream,
                     adj, W_lift, b_lift, W1, b1, W2, b2, W_ro, b_ro, ws);
  hipLaunchKernelGGL(gnn_mfma, dim3(B / 4), dim3(256), 0, stream,
                     x, (const char*)ws, o);
}

// Round 3
// 135.377 us; speedup vs baseline: 1.2801x; 1.2801x over previous
//
#include <hip/hip_runtime.h>

// GNN surrogate — r20: r19's half8-native state at the CORRECT reg budget.
// r19 post-mortem: __launch_bounds__(256,3) -> 168-reg unified budget split
// 84 VGPR + 84 AGPR (VGPR_Count=84, the r15/r16 signature) -> all state
// spilled: WRITE_SIZE 139 MB, scratch-BW-bound. The half8 restructure itself
// was never tested spill-free. This round: same structure, (256,2) = 256-reg
// budget (proven r17/r18). Live set < r18's (cat copies gone) -> expect zero
// scratch (r18 still wrote 2.6 MB).
// DO NOT raise min-waves-per-EU above 2 for this kernel: 168-reg budget
// ALWAYS spills the ~130-150-reg state. Occupancy must come from elsewhere.
// Also: prep parallelized (adjb over 8 blocks, v-sum 2 threads/col) to attack
// the constant ~75 us e2e-minus-gnn gap seen in r17/r18/r19.

typedef _Float16 f16;
typedef __attribute__((ext_vector_type(8))) _Float16 half8;
typedef __attribute__((ext_vector_type(4))) _Float16 half4;
typedef __attribute__((ext_vector_type(2))) __fp16 fp16x2;
typedef __attribute__((ext_vector_type(4))) float f32x4;

namespace {
constexpr int N = 128, H = 32;
constexpr int WS_ADJB = 0;       // f16 [8gi][4c][64lane][8] K=32 adj B-tiles (32768 B)
constexpr int WS_W0B  = 32768;   // f16 [2t][64lane][4]  W1eff K=16 B-tiles   (1024 B)
constexpr int WS_MB   = 33792;   // f16 [2l][2t][64lane][8] Meff K=32 B-tiles (4096 B)
constexpr int WS_BIAS = 37888;   // f32 [3][32]
constexpr int WS_V    = 38400;   // f32 [128]
constexpr int WS_U    = 38912;   // f32 [32]
constexpr int WS_C    = 39040;   // f32 [1]
}

static __device__ __forceinline__ half4 pk4(float a, float b, float c, float d) {
  union { half4 v; fp16x2 h[2]; } u;
  u.h[0] = __builtin_amdgcn_cvt_pkrtz(a, b);
  u.h[1] = __builtin_amdgcn_cvt_pkrtz(c, d);
  return u.v;
}
static __device__ __forceinline__ half4 relupk(f32x4 c) {
  const half4 z = {};
  return __builtin_elementwise_max(pk4(c[0], c[1], c[2], c[3]), z);
}
static __device__ __forceinline__ half4 pkc(f32x4 c) {
  return pk4(c[0], c[1], c[2], c[3]);
}
static __device__ __forceinline__ half8 cat(half4 lo, half4 hi) {
  return __builtin_shufflevector(lo, hi, 0, 1, 2, 3, 4, 5, 6, 7);
}

#define MF(A, B, C)   __builtin_amdgcn_mfma_f32_16x16x16f16((A), (B), (C), 0, 0, 0)
#define MF32(A, B, C) __builtin_amdgcn_mfma_f32_16x16x32_f16((A), (B), (C), 0, 0, 0)

// ---- prep: blocks 1..8 fill adjb (one gi each); block 0 does the rest ----
__global__ void prep(const float* __restrict__ adj,
                     const float* __restrict__ W_lift,
                     const float* __restrict__ b_lift,
                     const float* __restrict__ W1,
                     const float* __restrict__ b1,
                     const float* __restrict__ W2,
                     const float* __restrict__ b2,
                     const float* __restrict__ W_ro,
                     const float* __restrict__ b_ro,
                     char* __restrict__ ws) {
  const int tid = threadIdx.x;
  f16* adjb  = (f16*)(ws + WS_ADJB);
  f16* w0b   = (f16*)(ws + WS_W0B);
  f16* mb    = (f16*)(ws + WS_MB);
  float* bia = (float*)(ws + WS_BIAS);
  float* v   = (float*)(ws + WS_V);
  float* u   = (float*)(ws + WS_U);
  float* cp  = (float*)(ws + WS_C);

  if (blockIdx.x != 0) {
    // K=32 adjacency B-tiles, one gi per block.
    const int e = (blockIdx.x - 1) * 256 + tid;
    const int gi = e >> 8, c = (e >> 6) & 3, lane = e & 63;
    const int lr = lane & 15, q = lane >> 4;
    const float* src = adj + (gi * 16 + lr) * N + c * 32;
    f16* dst = adjb + e * 8;
#pragma unroll
    for (int j = 0; j < 8; ++j) {
      const int col = (j < 4) ? (4 * q + j) : (12 + 4 * q + j);  // lambda
      dst[j] = (f16)src[col];
    }
    return;
  }

  __shared__ float tmp[3][H][H];
  __shared__ float vpart[2][N];
  // column sums of adj, 2 threads per column
  {
    const int c = tid & 127, h = tid >> 7;
    float s = 0.f;
    for (int i = h * 64; i < h * 64 + 64; ++i) s += adj[i * N + c];
    vpart[h][c] = s;
  }
  for (int idx = tid; idx < 3 * H * H; idx += 256) {
    const int l = idx >> 10, rem = idx & 1023;
    const int k = rem >> 5, fo = rem & 31;
    float val = 0.f;
    if (l == 0) {
      if (k < 3) for (int c = 0; c < H; ++c) val += W_lift[k * H + c] * W1[c * H + fo];
    } else {
      const float* w2l = W2 + (l - 1) * H * H;
      const float* w1n = W1 + l * H * H;
      for (int c = 0; c < H; ++c) val += w2l[k * H + c] * w1n[c * H + fo];
    }
    tmp[l][k][fo] = val;
  }
  if (tid < H) {
    float s0 = b1[tid], s1 = b1[H + tid], s2 = b1[2 * H + tid];
    for (int c = 0; c < H; ++c) {
      s0 += b_lift[c] * W1[c * H + tid];
      s1 += b2[c] * W1[H * H + c * H + tid];
      s2 += b2[H + c] * W1[2 * H * H + c * H + tid];
    }
    bia[tid] = s0; bia[H + tid] = s1; bia[2 * H + tid] = s2;
    float su = 0.f;
    for (int c = 0; c < H; ++c) su += W2[2 * H * H + tid * H + c] * W_ro[c];
    u[tid] = su;
  }
  __syncthreads();
  if (tid < N) v[tid] = (vpart[0][tid] + vpart[1][tid]) * (1.0f / N);
  for (int e = tid; e < 512; e += 256) {
    const int t = e >> 8, lane = (e >> 2) & 63, j = e & 3;
    const int lr = lane & 15, q = lane >> 4;
    w0b[e] = (f16)tmp[0][q * 4 + j][t * 16 + lr];
  }
  for (int e = tid; e < 2048; e += 256) {
    const int l = e >> 10, rem = e & 1023;
    const int t = rem >> 9, lane = (rem >> 3) & 63, j = rem & 7;
    const int lr = lane & 15, q = lane >> 4;
    const int k = (j < 4) ? (4 * q + j) : (12 + 4 * q + j);  // lambda
    mb[e] = (f16)tmp[1 + l][k][t * 16 + lr];
  }
  __syncthreads();
  if (tid < 64) {
    float s = (vpart[0][tid] + vpart[1][tid] + vpart[0][64 + tid] + vpart[1][64 + tid])
              * (1.0f / N);
#pragma unroll
    for (int off = 32; off > 0; off >>= 1) s += __shfl_down(s, off, 64);
    if (tid == 0) {
      float c2r = 0.f;
      for (int k = 0; k < H; ++k) c2r += b2[2 * H + k] * W_ro[k];
      cp[0] = c2r * s + b_ro[0];
    }
  }
}

__global__ __launch_bounds__(256, 2)
void gnn_mfma(const float* __restrict__ x,
              const char* __restrict__ ws,
              float* __restrict__ out) {
  const f16* adjb  = (const f16*)(ws + WS_ADJB);
  const f16* w0b   = (const f16*)(ws + WS_W0B);
  const f16* mb    = (const f16*)(ws + WS_MB);
  const float* bia = (const float*)(ws + WS_BIAS);
  const float* v   = (const float*)(ws + WS_V);
  const float* u   = (const float*)(ws + WS_U);
  const float* cp  = (const float*)(ws + WS_C);

  const int tid  = threadIdx.x;
  const int wave = tid >> 6;
  const int lane = tid & 63;
  const int lrow = lane & 15;
  const int quad = lane >> 4;
  const int b    = blockIdx.x * 4 + wave;

  const f32x4 zero = {0.f, 0.f, 0.f, 0.f};

  // Persistent state: 8 half8 (32 VGPR) ping-ponged with 8 half8 (32 VGPR).
  // ca_p/cb_p = [fout block][node-pair 2p,2p+1]  (G-stage A operands)
  // pf_g      = [fout blocks 0|1 concat][group g] (L-stage A operands)
  half8 ca0, ca1, ca2, ca3, cb0, cb1, cb2, cb3;
  half8 pf0, pf1, pf2, pf3, pf4, pf5, pf6, pf7;

  // ---- L0: T0 = relu(x·W1eff + b0), K=16 MFMA, emits G-friendly cats ----
  {
    const half4 w0 = *(const half4*)(w0b + (0 * 64 + lane) * 4);
    const half4 w1 = *(const half4*)(w0b + (1 * 64 + lane) * 4);
    const float bb0 = bia[lrow], bb1 = bia[16 + lrow];
    const f32x4 bi0 = {bb0, bb0, bb0, bb0};
    const f32x4 bi1 = {bb1, bb1, bb1, bb1};
#define L0PAIR(g, CA, CB)                                                    \
    {                                                                        \
      half4 xa0 = {}, xa1 = {};                                              \
      if (quad == 0) {                                                       \
        const float* xr0 = x + ((size_t)b * N + (g) * 16 + lrow) * 3;        \
        const float* xr1 = x + ((size_t)b * N + ((g) + 1) * 16 + lrow) * 3;  \
        xa0 = pk4(xr0[0], xr0[1], xr0[2], 0.f);                              \
        xa1 = pk4(xr1[0], xr1[1], xr1[2], 0.f);                              \
      }                                                                      \
      CA = cat(relupk(MF(xa0, w0, bi0)), relupk(MF(xa1, w0, bi0)));          \
      CB = cat(relupk(MF(xa0, w1, bi1)), relupk(MF(xa1, w1, bi1)));          \
    }
    L0PAIR(0, ca0, cb0) L0PAIR(2, ca1, cb1) L0PAIR(4, ca2, cb2) L0PAIR(6, ca3, cb3)
#undef L0PAIR
  }

  // G: pf_g = cat over fout blocks of P^T[t][nodes gi]; K=32 MFMAs.
#define GSTEP(gi, PF)                                                        \
  {                                                                          \
    f32x4 a0 = zero, a1 = zero;                                              \
    const f16* ab = adjb + ((gi) * 256 + lane) * 8;                          \
    half8 bt;                                                                \
    bt = *(const half8*)(ab + 0 * 512);                                      \
    a0 = MF32(ca0, bt, a0); a1 = MF32(cb0, bt, a1);                          \
    bt = *(const half8*)(ab + 1 * 512);                                      \
    a0 = MF32(ca1, bt, a0); a1 = MF32(cb1, bt, a1);                          \
    bt = *(const half8*)(ab + 2 * 512);                                      \
    a0 = MF32(ca2, bt, a0); a1 = MF32(cb2, bt, a1);                          \
    bt = *(const half8*)(ab + 3 * 512);                                      \
    a0 = MF32(ca3, bt, a0); a1 = MF32(cb3, bt, a1);                          \
    PF = cat(pkc(a0), pkc(a1));                                              \
  }
#define GALL()                                                               \
  GSTEP(0, pf0) GSTEP(1, pf1) GSTEP(2, pf2) GSTEP(3, pf3)                    \
  GSTEP(4, pf4) GSTEP(5, pf5) GSTEP(6, pf6) GSTEP(7, pf7)

  GALL()   // G0

  // L1: consumes pf pairs, emits G-friendly cats directly.
  {
    const f16* mbl = mb + 0 * 1024;
    const half8 m0 = *(const half8*)(mbl + (0 * 64 + lane) * 8);
    const half8 m1 = *(const half8*)(mbl + (1 * 64 + lane) * 8);
    const float bb0 = bia[H + lrow], bb1 = bia[H + 16 + lrow];
    const f32x4 bi0 = {bb0, bb0, bb0, bb0};
    const f32x4 bi1 = {bb1, bb1, bb1, bb1};
#define L1PAIR(PFA, PFB, CA, CB)                                             \
    {                                                                        \
      f32x4 c0a = MF32(PFA, m0, bi0);                                        \
      f32x4 c1a = MF32(PFA, m1, bi1);                                        \
      f32x4 c0b = MF32(PFB, m0, bi0);                                        \
      f32x4 c1b = MF32(PFB, m1, bi1);                                        \
      CA = cat(relupk(c0a), relupk(c0b));                                    \
      CB = cat(relupk(c1a), relupk(c1b));                                    \
    }
    L1PAIR(pf0, pf1, ca0, cb0) L1PAIR(pf2, pf3, ca1, cb1)
    L1PAIR(pf4, pf5, ca2, cb2) L1PAIR(pf6, pf7, ca3, cb3)
#undef L1PAIR
  }

  GALL()   // G1
#undef GALL
#undef GSTEP

  // ---- L2 + folded readout: consumes pf_g directly ----
  {
    const f16* mbl = mb + 1 * 1024;
    const half8 m0 = *(const half8*)(mbl + (0 * 64 + lane) * 8);
    const half8 m1 = *(const half8*)(mbl + (1 * 64 + lane) * 8);
    const float bb0 = bia[2 * H + lrow], bb1 = bia[2 * H + 16 + lrow];
    const f32x4 bi0 = {bb0, bb0, bb0, bb0};
    const f32x4 bi1 = {bb1, bb1, bb1, bb1};
    const float u0 = u[lrow], u1 = u[16 + lrow];
    float partial = 0.f;
#define L2G(g, PF)                                                           \
    {                                                                        \
      f32x4 c0 = MF32(PF, m0, bi0);                                          \
      f32x4 c1 = MF32(PF, m1, bi1);                                          \
      const float4 vv = *(const float4*)(v + (g) * 16 + quad * 4);           \
      partial += (fmaxf(c0[0], 0.f) * vv.x + fmaxf(c0[1], 0.f) * vv.y +      \
                  fmaxf(c0[2], 0.f) * vv.z + fmaxf(c0[3], 0.f) * vv.w) * u0 +\
                 (fmaxf(c1[0], 0.f) * vv.x + fmaxf(c1[1], 0.f) * vv.y +      \
                  fmaxf(c1[2], 0.f) * vv.z + fmaxf(c1[3], 0.f) * vv.w) * u1; \
    }
    L2G(0, pf0) L2G(1, pf1) L2G(2, pf2) L2G(3, pf3)
    L2G(4, pf4) L2G(5, pf5) L2G(6, pf6) L2G(7, pf7)
#undef L2G
#pragma unroll
    for (int off = 32; off > 0; off >>= 1) partial += __shfl_down(partial, off, 64);
    if (lane == 0) out[b] = partial + cp[0];
  }
}

extern "C" void kernel_launch(void* const* d_in, const int* in_sizes, int n_in,
                              void* d_out, int out_size, void* d_ws, size_t ws_size,
                              hipStream_t stream) {
  const float* x      = (const float*)d_in[0];
  const float* adj    = (const float*)d_in[1];
  const float* W_lift = (const float*)d_in[2];
  const float* b_lift = (const float*)d_in[3];
  const float* W1     = (const float*)d_in[4];
  const float* b1     = (const float*)d_in[5];
  const float* W2     = (const float*)d_in[6];
  const float* b2     = (const float*)d_in[7];
  const float* W_ro   = (const float*)d_in[8];
  const float* b_ro   = (const float*)d_in[9];
  char* ws = (char*)d_ws;
  float* o = (float*)d_out;

  const int B = in_sizes[0] / (N * 3);   // 16384
  hipLaunchKernelGGL(prep, dim3(9), dim3(256), 0, stream,
                     adj, W_lift, b_lift, W1, b1, W2, b2, W_ro, b_ro, ws);
  hipLaunchKernelGGL(gnn_mfma, dim3(B / 4), dim3(256), 0, stream,
                     x, (const char*)ws, o);
}